// Round 1
// baseline (6859.920 us; speedup 1.0000x reference)
//
#include <hip/hip_runtime.h>
#include <math.h>

#define Bb 64
#define Ll 512
#define Dd 512
#define Ff 2048
#define Ee 8

typedef _Float16 half8 __attribute__((ext_vector_type(8)));
typedef float f32x4 __attribute__((ext_vector_type(4)));

// Fused MoE MLP: per-wg (b, 64-token) tile; loops active experts; Phase A
// (X@W1 -> gelu -> gate-scale -> Hs LDS), Phase B (Hs@W2 -> OutAcc regs).
// fp16 MFMA 16x16x32, fp32 accumulate. X held in registers as A-fragments.
__global__ __launch_bounds__(512, 2)
void moe_fused(const float* __restrict__ x, const float* __restrict__ logits,
               const int* __restrict__ masks, const float* __restrict__ w1,
               const float* __restrict__ b1, const float* __restrict__ w2,
               const float* __restrict__ b2, float* __restrict__ out)
{
    // Phase A view: [n=64][k=128 pad 136]; Phase B view: [n=128][k=64 pad 72]
    __shared__ alignas(16) _Float16 Ws[2][9216];
    __shared__ alignas(16) _Float16 Hs[64 * 72];   // [m=64][k=64 pad 72]

    const int tid  = threadIdx.x;
    const int wv   = tid >> 6;
    const int lane = tid & 63;
    const int nl   = lane & 15;   // MFMA row/col index
    const int q    = lane >> 4;   // MFMA quad
    const int mt   = wv >> 1;     // m-tile (0..3), wave pair shares it
    const int wh   = wv & 1;      // n-split within the pair

    const int bid = blockIdx.x;
    const int b   = bid >> 3;
    const int l0  = (bid & 7) * 64;

    // ---- gates (uniform across block; recomputed per thread, trivial) ----
    float gate[Ee];
    {
        float lg[Ee];
        float mx = -1e30f;
        #pragma unroll
        for (int e = 0; e < Ee; ++e) { lg[e] = logits[b * Ee + e]; mx = fmaxf(mx, lg[e]); }
        float s = 0.f;
        #pragma unroll
        for (int e = 0; e < Ee; ++e) { float ex = expf(lg[e] - mx); s += ex; lg[e] = ex; }
        float gs = 0.f;
        #pragma unroll
        for (int e = 0; e < Ee; ++e) {
            float r = lg[e] / s;
            r = (masks[b * Ee + e] == 1) ? r : 0.f;
            lg[e] = r; gs += r;
        }
        const float inv = 1.f / (gs + 1e-9f);
        #pragma unroll
        for (int e = 0; e < Ee; ++e) gate[e] = lg[e] * inv;
    }

    // ---- persistent A fragments: A[m=nl][k=q*8+j], 16 ksteps over K=512 ----
    half8 afrag[16];
    {
        const float* xrow = x + (size_t)(b * Ll + l0 + mt * 16 + nl) * Dd;
        #pragma unroll
        for (int ks = 0; ks < 16; ++ks) {
            const int c0 = ks * 32 + q * 8;
            const f32x4 u0 = *(const f32x4*)(xrow + c0);
            const f32x4 u1 = *(const f32x4*)(xrow + c0 + 4);
            half8 a;
            a[0]=(_Float16)u0[0]; a[1]=(_Float16)u0[1]; a[2]=(_Float16)u0[2]; a[3]=(_Float16)u0[3];
            a[4]=(_Float16)u1[0]; a[5]=(_Float16)u1[1]; a[6]=(_Float16)u1[2]; a[7]=(_Float16)u1[3];
            afrag[ks] = a;
        }
    }

    f32x4 oacc[16];
    #pragma unroll
    for (int i = 0; i < 16; ++i) oacc[i] = (f32x4){0.f, 0.f, 0.f, 0.f};

    #pragma unroll 1
    for (int e = 0; e < Ee; ++e) {
        const float g = gate[e];
        if (g == 0.f) continue;                 // block-uniform branch
        const float* W1e = w1 + (size_t)e * Dd * Ff;
        const float* W2e = w2 + (size_t)e * Ff * Dd;
        const float* b1e = b1 + (size_t)e * Ff;

        #pragma unroll 1
        for (int fc = 0; fc < Ff; fc += 64) {
            // =================== Phase A: H[64,64] = X @ W1[:,fc:fc+64] ===================
            f32x4 hacc[2];
            hacc[0] = (f32x4){0,0,0,0}; hacc[1] = (f32x4){0,0,0,0};

            f32x4 pre[4];
            // stage k-chunk 0 (W1[kc..kc+128][fc..fc+64] -> transposed fp16 LDS)
            #pragma unroll
            for (int j = 0; j < 4; ++j) {
                const int i = tid + j * 512;
                const int kk = i >> 4, n4 = (i & 15) * 4;
                pre[j] = *(const f32x4*)(W1e + (size_t)kk * Ff + (fc + n4));
            }
            #pragma unroll
            for (int j = 0; j < 4; ++j) {
                const int i = tid + j * 512;
                const int kk = i >> 4, n4 = (i & 15) * 4;
                Ws[0][(n4+0)*136 + kk] = (_Float16)pre[j][0];
                Ws[0][(n4+1)*136 + kk] = (_Float16)pre[j][1];
                Ws[0][(n4+2)*136 + kk] = (_Float16)pre[j][2];
                Ws[0][(n4+3)*136 + kk] = (_Float16)pre[j][3];
            }
            __syncthreads();

            #pragma unroll
            for (int kci = 0; kci < 4; ++kci) {
                if (kci < 3) {   // prefetch next chunk (loads overlap MFMA below)
                    #pragma unroll
                    for (int j = 0; j < 4; ++j) {
                        const int i = tid + j * 512;
                        const int kk = i >> 4, n4 = (i & 15) * 4;
                        pre[j] = *(const f32x4*)(W1e + (size_t)((kci+1)*128 + kk) * Ff + (fc + n4));
                    }
                }
                const int bufi = kci & 1;
                #pragma unroll
                for (int kk8 = 0; kk8 < 4; ++kk8) {
                    const half8 a = afrag[kci * 4 + kk8];
                    #pragma unroll
                    for (int jn = 0; jn < 2; ++jn) {
                        const int fn = wh * 2 + jn;
                        const half8 bf = *(const half8*)&Ws[bufi][(fn*16 + nl)*136 + kk8*32 + q*8];
                        hacc[jn] = __builtin_amdgcn_mfma_f32_16x16x32_f16(a, bf, hacc[jn], 0, 0, 0);
                    }
                }
                if (kci < 3) {
                    const int nb = (kci + 1) & 1;
                    #pragma unroll
                    for (int j = 0; j < 4; ++j) {
                        const int i = tid + j * 512;
                        const int kk = i >> 4, n4 = (i & 15) * 4;
                        Ws[nb][(n4+0)*136 + kk] = (_Float16)pre[j][0];
                        Ws[nb][(n4+1)*136 + kk] = (_Float16)pre[j][1];
                        Ws[nb][(n4+2)*136 + kk] = (_Float16)pre[j][2];
                        Ws[nb][(n4+3)*136 + kk] = (_Float16)pre[j][3];
                    }
                }
                __syncthreads();
            }

            // epilogue A: bias + exact gelu + gate scale -> Hs (A-operand layout [m][k])
            #pragma unroll
            for (int jn = 0; jn < 2; ++jn) {
                const int fn = wh * 2 + jn;
                const float bv = b1e[fc + fn * 16 + nl];
                #pragma unroll
                for (int r = 0; r < 4; ++r) {
                    const float v  = hacc[jn][r] + bv;
                    const float gl = 0.5f * v * (1.f + erff(v * 0.70710678118654752f));
                    Hs[(mt*16 + q*4 + r)*72 + fn*16 + nl] = (_Float16)(g * gl);
                }
            }

            // =================== Phase B: OutAcc += Hs @ W2[fc:fc+64, :] ===================
            // stage n-chunk 0 (W2[fc+kk][n..n+128] -> transposed fp16 LDS)
            #pragma unroll
            for (int j = 0; j < 4; ++j) {
                const int i = tid + j * 512;
                const int kk = i >> 5, n4 = (i & 31) * 4;
                pre[j] = *(const f32x4*)(W2e + (size_t)(fc + kk) * Dd + n4);
            }
            #pragma unroll
            for (int j = 0; j < 4; ++j) {
                const int i = tid + j * 512;
                const int kk = i >> 5, n4 = (i & 31) * 4;
                Ws[0][(n4+0)*72 + kk] = (_Float16)pre[j][0];
                Ws[0][(n4+1)*72 + kk] = (_Float16)pre[j][1];
                Ws[0][(n4+2)*72 + kk] = (_Float16)pre[j][2];
                Ws[0][(n4+3)*72 + kk] = (_Float16)pre[j][3];
            }
            __syncthreads();   // also publishes Hs

            half8 ha[2];
            #pragma unroll
            for (int kk8 = 0; kk8 < 2; ++kk8)
                ha[kk8] = *(const half8*)&Hs[(mt*16 + nl)*72 + kk8*32 + q*8];

            #pragma unroll
            for (int nci = 0; nci < 4; ++nci) {
                if (nci < 3) {
                    #pragma unroll
                    for (int j = 0; j < 4; ++j) {
                        const int i = tid + j * 512;
                        const int kk = i >> 5, n4 = (i & 31) * 4;
                        pre[j] = *(const f32x4*)(W2e + (size_t)(fc + kk) * Dd + (nci+1)*128 + n4);
                    }
                }
                const int bufi = nci & 1;
                #pragma unroll
                for (int kk8 = 0; kk8 < 2; ++kk8) {
                    #pragma unroll
                    for (int jn = 0; jn < 4; ++jn) {
                        const int ntl = jn * 2 + wh;
                        const half8 bf = *(const half8*)&Ws[bufi][(ntl*16 + nl)*72 + kk8*32 + q*8];
                        oacc[nci*4 + jn] = __builtin_amdgcn_mfma_f32_16x16x32_f16(ha[kk8], bf, oacc[nci*4 + jn], 0, 0, 0);
                    }
                }
                if (nci < 3) {
                    const int nb = (nci + 1) & 1;
                    #pragma unroll
                    for (int j = 0; j < 4; ++j) {
                        const int i = tid + j * 512;
                        const int kk = i >> 5, n4 = (i & 31) * 4;
                        Ws[nb][(n4+0)*72 + kk] = (_Float16)pre[j][0];
                        Ws[nb][(n4+1)*72 + kk] = (_Float16)pre[j][1];
                        Ws[nb][(n4+2)*72 + kk] = (_Float16)pre[j][2];
                        Ws[nb][(n4+3)*72 + kk] = (_Float16)pre[j][3];
                    }
                }
                __syncthreads();
            }
        }
    }

    // ---- epilogue: add sum_e gate[e]*b2[e,:] and store fp32 ----
    #pragma unroll
    for (int i = 0; i < 16; ++i) {
        const int dcol = (i * 2 + wh) * 16 + nl;
        float bb = 0.f;
        #pragma unroll
        for (int e = 0; e < Ee; ++e) bb += gate[e] * b2[e * Dd + dcol];
        const size_t base = (size_t)(b * Ll + l0 + mt * 16 + q * 4) * Dd + dcol;
        out[base]        = oacc[i][0] + bb;
        out[base + Dd]   = oacc[i][1] + bb;
        out[base + 2*Dd] = oacc[i][2] + bb;
        out[base + 3*Dd] = oacc[i][3] + bb;
    }
}

__global__ void moe_loss(const float* __restrict__ logits, const int* __restrict__ masks,
                         float* __restrict__ loss_out)
{
    const int b = threadIdx.x;   // 64 threads = 1 wave
    float lg[Ee];
    float mx = -1e30f;
    #pragma unroll
    for (int e = 0; e < Ee; ++e) { lg[e] = logits[b * Ee + e]; mx = fmaxf(mx, lg[e]); }
    float s = 0.f;
    #pragma unroll
    for (int e = 0; e < Ee; ++e) { float ex = expf(lg[e] - mx); s += ex; lg[e] = ex; }
    float rs = 0.f;
    #pragma unroll
    for (int e = 0; e < Ee; ++e) if (masks[b * Ee + e] == 1) rs += lg[e] / s;
    #pragma unroll
    for (int off = 32; off > 0; off >>= 1) rs += __shfl_down(rs, off);
    if (b == 0) {
        const float t = 1.f - rs / (float)Bb;
        loss_out[0] = t * t;
    }
}

extern "C" void kernel_launch(void* const* d_in, const int* in_sizes, int n_in,
                              void* d_out, int out_size, void* d_ws, size_t ws_size,
                              hipStream_t stream)
{
    const float* x      = (const float*)d_in[0];
    const float* logits = (const float*)d_in[1];
    const int*   masks  = (const int*)d_in[2];
    const float* w1     = (const float*)d_in[3];
    const float* b1     = (const float*)d_in[4];
    const float* w2     = (const float*)d_in[5];
    const float* b2     = (const float*)d_in[6];
    float* out = (float*)d_out;

    hipLaunchKernelGGL(moe_fused, dim3(Bb * (Ll / 64)), dim3(512), 0, stream,
                       x, logits, masks, w1, b1, w2, b2, out);
    hipLaunchKernelGGL(moe_loss, dim3(1), dim3(64), 0, stream,
                       logits, masks, out + (size_t)Bb * Ll * Dd);
}

// Round 2
// 4094.181 us; speedup vs baseline: 1.6755x; 1.6755x over previous
//
#include <hip/hip_runtime.h>
#include <math.h>

#define Bb 64
#define Ll 512
#define Dd 512
#define Ff 2048
#define Ee 8

typedef _Float16 half_t;
typedef _Float16 half8 __attribute__((ext_vector_type(8)));
typedef float f32x4 __attribute__((ext_vector_type(4)));

// ws layout (halves): W1t [E][F][D] at 0 ; W2t [E][D][F] at W2T_OFF
#define W2T_OFF (Ee * Dd * Ff)

__device__ __forceinline__ void dma16(const half_t* g, half_t* l) {
    // global -> LDS direct DMA, 16B per lane; LDS dst = uniform base + lane*16
    __builtin_amdgcn_global_load_lds((const __attribute__((address_space(1))) void*)g,
                                     (__attribute__((address_space(3))) void*)l, 16, 0, 0);
}

// ---------------- prep: fp32 [R][C] -> fp16 [C][R] transpose ----------------
__global__ __launch_bounds__(256)
void prep_transpose(const float* __restrict__ w1, const float* __restrict__ w2,
                    half_t* __restrict__ ws)
{
    __shared__ half_t T[64 * 72];
    int bid = blockIdx.x;
    const float* src; half_t* dst; int R, C, r0, c0;
    if (bid < 2048) {            // W1 per e: R=512(d), C=2048(f): 8 x 32 tiles
        int e = bid >> 8, t = bid & 255;
        r0 = (t >> 5) * 64; c0 = (t & 31) * 64;
        src = w1 + (size_t)e * Dd * Ff;
        dst = ws + (size_t)e * Ff * Dd;
        R = Dd; C = Ff;
    } else {                     // W2 per e: R=2048(f), C=512(d): 32 x 8 tiles
        bid -= 2048;
        int e = bid >> 8, t = bid & 255;
        r0 = (t >> 3) * 64; c0 = (t & 7) * 64;
        src = w2 + (size_t)e * Ff * Dd;
        dst = ws + W2T_OFF + (size_t)e * Dd * Ff;
        R = Ff; C = Dd;
    }
    const int cx = threadIdx.x & 63, ry = threadIdx.x >> 6;
    #pragma unroll
    for (int j = 0; j < 16; ++j) {
        int r = ry * 16 + j;
        T[cx * 72 + r] = (half_t)src[(size_t)(r0 + r) * C + c0 + cx];
    }
    __syncthreads();
    const int rx = threadIdx.x & 7;
    #pragma unroll
    for (int it = 0; it < 2; ++it) {
        int cr = (threadIdx.x >> 3) + it * 32;
        *(half8*)&dst[(size_t)(c0 + cr) * R + r0 + rx * 8] = *(half8*)&T[cr * 72 + rx * 8];
    }
}

// ---------------- main fused MoE ----------------
// Block = (b, 64-token tile), 512 thr / 8 waves. Per active expert:
//   Phase A (per fc 128-wide): H = gelu(X@W1t^T + b1)*gate into Hs (fp16, swizzled)
//   Phase B: OutAcc += Hs @ W2t^T
// Weight tiles 128x128 fp16 staged via global_load_lds, double-buffered,
// prefetched one step ahead. XOR swizzle (blk ^= row&15) applied at DMA src
// so all ds_read_b128 are conflict-free without padding.
__global__ __launch_bounds__(512, 4)
void moe_main(const float* __restrict__ x, const float* __restrict__ logits,
              const int* __restrict__ masks, const half_t* __restrict__ ws,
              const float* __restrict__ b1, const float* __restrict__ b2,
              float* __restrict__ out)
{
    __shared__ half_t Wbuf[2][128 * 128];   // 2 x 32KB
    __shared__ half_t Hs[64 * 128];         // 16KB  (total 80KB -> 2 blocks/CU)

    const int tid  = threadIdx.x;
    const int wv   = tid >> 6;
    const int lane = tid & 63;
    const int nl   = lane & 15;
    const int q    = lane >> 4;
    const int mt   = wv >> 1;     // m-tile (tokens), both phases
    const int nh   = wv & 1;      // n-split within pair

    const int bid = blockIdx.x;
    const int b   = bid & 63;     // same-b blocks land on same XCD (bid%8==b%8)
    const int l0  = (bid >> 6) * 64;

    // DMA lane decomposition
    const int rl = lane >> 4;     // row-within-4 for staging
    const int pcl = lane & 15;    // physical 16B block slot

    // ---- gates ----
    float gate[Ee];
    {
        float lg[Ee];
        float mx = -1e30f;
        #pragma unroll
        for (int e = 0; e < Ee; ++e) { lg[e] = logits[b * Ee + e]; mx = fmaxf(mx, lg[e]); }
        float s = 0.f;
        #pragma unroll
        for (int e = 0; e < Ee; ++e) { float ex = expf(lg[e] - mx); s += ex; lg[e] = ex; }
        float gs = 0.f;
        #pragma unroll
        for (int e = 0; e < Ee; ++e) {
            float r = lg[e] / s;
            r = (masks[b * Ee + e] == 1) ? r : 0.f;
            lg[e] = r; gs += r;
        }
        const float inv = 1.f / (gs + 1e-9f);
        #pragma unroll
        for (int e = 0; e < Ee; ++e) gate[e] = lg[e] * inv;
    }

    // ---- persistent X A-fragments: A[m=nl][k=q*8+j], 16 ksteps over K=512 ----
    half8 afrag[16];
    {
        const float* xrow = x + (size_t)(b * Ll + l0 + mt * 16 + nl) * Dd;
        #pragma unroll
        for (int ks = 0; ks < 16; ++ks) {
            const int c0 = ks * 32 + q * 8;
            const f32x4 u0 = *(const f32x4*)(xrow + c0);
            const f32x4 u1 = *(const f32x4*)(xrow + c0 + 4);
            half8 a;
            a[0]=(half_t)u0[0]; a[1]=(half_t)u0[1]; a[2]=(half_t)u0[2]; a[3]=(half_t)u0[3];
            a[4]=(half_t)u1[0]; a[5]=(half_t)u1[1]; a[6]=(half_t)u1[2]; a[7]=(half_t)u1[3];
            afrag[ks] = a;
        }
    }

    f32x4 oacc[16];
    #pragma unroll
    for (int i = 0; i < 16; ++i) oacc[i] = (f32x4){0.f, 0.f, 0.f, 0.f};

    #pragma unroll 1
    for (int e = 0; e < Ee; ++e) {
        const float g = gate[e];
        if (g == 0.f) continue;                       // block-uniform skip
        const half_t* W1te = ws + (size_t)e * Ff * Dd;            // [F][D]
        const half_t* W2te = ws + W2T_OFF + (size_t)e * Dd * Ff;  // [D][F]
        const float*  b1e  = b1 + (size_t)e * Ff;

        // prologue: stage A-tile (fc=0, kc=0) into buf 0
        #pragma unroll
        for (int s = 0; s < 4; ++s) {
            const int row = wv * 16 + s * 4 + rl;
            const int c = pcl ^ (row & 15);
            dma16(W1te + (size_t)row * Dd + c * 8,
                  &Wbuf[0][(wv * 16 + s * 4) * 128]);
        }

        #pragma unroll 1
        for (int fci = 0; fci < 16; ++fci) {
            const int f0 = fci * 128;
            f32x4 hacc[4];
            #pragma unroll
            for (int i = 0; i < 4; ++i) hacc[i] = (f32x4){0.f,0.f,0.f,0.f};

            // ---------- Phase A: 4 K-chunks of 128 ----------
            #pragma unroll
            for (int kc = 0; kc < 4; ++kc) {
                __syncthreads();   // buf[kc&1] DMA (issued prev step) complete
                if (kc < 3) {      // prefetch A-tile kc+1
                    #pragma unroll
                    for (int s = 0; s < 4; ++s) {
                        const int row = wv * 16 + s * 4 + rl;
                        const int c = pcl ^ (row & 15);
                        dma16(W1te + (size_t)(f0 + row) * Dd + (kc + 1) * 128 + c * 8,
                              &Wbuf[(kc & 1) ^ 1][(wv * 16 + s * 4) * 128]);
                    }
                } else {           // prefetch B-tile nc=0
                    #pragma unroll
                    for (int s = 0; s < 4; ++s) {
                        const int row = wv * 16 + s * 4 + rl;
                        const int c = pcl ^ (row & 15);
                        dma16(W2te + (size_t)row * Ff + f0 + c * 8,
                              &Wbuf[(kc & 1) ^ 1][(wv * 16 + s * 4) * 128]);
                    }
                }
                // compute from buf[kc&1]
                #pragma unroll
                for (int ks = 0; ks < 4; ++ks) {
                    const half8 a = afrag[kc * 4 + ks];
                    #pragma unroll
                    for (int nf = 0; nf < 4; ++nf) {
                        const int row = nh * 64 + nf * 16 + nl;
                        const half8 bf = *(const half8*)&Wbuf[kc & 1][row * 128 + (((ks * 4 + q) ^ nl) * 8)];
                        hacc[nf] = __builtin_amdgcn_mfma_f32_16x16x32_f16(a, bf, hacc[nf], 0, 0, 0);
                    }
                }
            }

            // ---------- epilogue A: bias + gelu + gate -> Hs (swizzled A-layout) ----------
            #pragma unroll
            for (int nf = 0; nf < 4; ++nf) {
                const int fl = nh * 64 + nf * 16 + nl;
                const float bv = b1e[f0 + fl];
                #pragma unroll
                for (int r = 0; r < 4; ++r) {
                    const int m = mt * 16 + q * 4 + r;
                    const float v  = hacc[nf][r] + bv;
                    const float gl = 0.5f * v * (1.f + erff(v * 0.70710678118654752f));
                    const int blk = (fl >> 3) ^ (m & 15);
                    Hs[m * 128 + blk * 8 + (fl & 7)] = (half_t)(g * gl);
                }
            }

            // ---------- Phase B: 4 n-chunks of 128 ----------
            half8 ha[4];
            #pragma unroll
            for (int nc = 0; nc < 4; ++nc) {
                __syncthreads();
                if (nc == 0) {     // Hs now published by all waves
                    #pragma unroll
                    for (int ks = 0; ks < 4; ++ks)
                        ha[ks] = *(const half8*)&Hs[(mt * 16 + nl) * 128 + (((ks * 4 + q) ^ nl) * 8)];
                }
                if (nc < 3) {      // prefetch B-tile nc+1
                    #pragma unroll
                    for (int s = 0; s < 4; ++s) {
                        const int row = wv * 16 + s * 4 + rl;
                        const int c = pcl ^ (row & 15);
                        dma16(W2te + (size_t)((nc + 1) * 128 + row) * Ff + f0 + c * 8,
                              &Wbuf[(nc & 1) ^ 1][(wv * 16 + s * 4) * 128]);
                    }
                } else if (fci < 15) {  // prefetch next fc A-tile kc=0
                    #pragma unroll
                    for (int s = 0; s < 4; ++s) {
                        const int row = wv * 16 + s * 4 + rl;
                        const int c = pcl ^ (row & 15);
                        dma16(W1te + (size_t)(f0 + 128 + row) * Dd + c * 8,
                              &Wbuf[(nc & 1) ^ 1][(wv * 16 + s * 4) * 128]);
                    }
                }
                // compute from buf[nc&1]
                #pragma unroll
                for (int ks = 0; ks < 4; ++ks) {
                    #pragma unroll
                    for (int t = 0; t < 4; ++t) {
                        const int lr = t * 32 + nh * 16 + nl;
                        const half8 bf = *(const half8*)&Wbuf[nc & 1][lr * 128 + (((ks * 4 + q) ^ nl) * 8)];
                        oacc[nc * 4 + t] = __builtin_amdgcn_mfma_f32_16x16x32_f16(ha[ks], bf, oacc[nc * 4 + t], 0, 0, 0);
                    }
                }
            }
        }
    }

    // ---- epilogue: add sum_e gate[e]*b2[e,:] and store fp32 ----
    #pragma unroll
    for (int nc = 0; nc < 4; ++nc) {
        #pragma unroll
        for (int t = 0; t < 4; ++t) {
            const int dcol = nc * 128 + t * 32 + nh * 16 + nl;
            float bb = 0.f;
            #pragma unroll
            for (int e = 0; e < Ee; ++e) bb += gate[e] * b2[e * Dd + dcol];
            const f32x4 v = oacc[nc * 4 + t];
            const size_t base = (size_t)(b * Ll + l0 + mt * 16 + q * 4) * Dd + dcol;
            out[base]          = v[0] + bb;
            out[base + Dd]     = v[1] + bb;
            out[base + 2 * Dd] = v[2] + bb;
            out[base + 3 * Dd] = v[3] + bb;
        }
    }
}

__global__ void moe_loss(const float* __restrict__ logits, const int* __restrict__ masks,
                         float* __restrict__ loss_out)
{
    const int b = threadIdx.x;   // 64 threads = 1 wave
    float lg[Ee];
    float mx = -1e30f;
    #pragma unroll
    for (int e = 0; e < Ee; ++e) { lg[e] = logits[b * Ee + e]; mx = fmaxf(mx, lg[e]); }
    float s = 0.f;
    #pragma unroll
    for (int e = 0; e < Ee; ++e) { float ex = expf(lg[e] - mx); s += ex; lg[e] = ex; }
    float rs = 0.f;
    #pragma unroll
    for (int e = 0; e < Ee; ++e) if (masks[b * Ee + e] == 1) rs += lg[e] / s;
    #pragma unroll
    for (int off = 32; off > 0; off >>= 1) rs += __shfl_down(rs, off);
    if (b == 0) {
        const float t = 1.f - rs / (float)Bb;
        loss_out[0] = t * t;
    }
}

extern "C" void kernel_launch(void* const* d_in, const int* in_sizes, int n_in,
                              void* d_out, int out_size, void* d_ws, size_t ws_size,
                              hipStream_t stream)
{
    const float* x      = (const float*)d_in[0];
    const float* logits = (const float*)d_in[1];
    const int*   masks  = (const int*)d_in[2];
    const float* w1     = (const float*)d_in[3];
    const float* b1     = (const float*)d_in[4];
    const float* w2     = (const float*)d_in[5];
    const float* b2     = (const float*)d_in[6];
    float* out = (float*)d_out;
    half_t* ws = (half_t*)d_ws;

    hipLaunchKernelGGL(prep_transpose, dim3(4096), dim3(256), 0, stream, w1, w2, ws);
    hipLaunchKernelGGL(moe_main, dim3(512), dim3(512), 0, stream,
                       x, logits, masks, ws, b1, b2, out);
    hipLaunchKernelGGL(moe_loss, dim3(1), dim3(64), 0, stream,
                       logits, masks, out + (size_t)Bb * Ll * Dd);
}

// Round 3
// 2380.041 us; speedup vs baseline: 2.8823x; 1.7202x over previous
//
#include <hip/hip_runtime.h>
#include <math.h>

#define Bb 64
#define Ll 512
#define Dd 512
#define Ff 2048
#define Ee 8

typedef _Float16 half_t;
typedef _Float16 half8 __attribute__((ext_vector_type(8)));
typedef float f32x4 __attribute__((ext_vector_type(4)));

// ws layout (halves): W1t [E][F][D] at 0 ; W2t [E][D][F] at W2T_OFF
#define W2T_OFF (Ee * Dd * Ff)

__device__ __forceinline__ void dma16(const half_t* g, half_t* l) {
    // global -> LDS direct DMA, 16B per lane; LDS dst = uniform base + lane*16
    __builtin_amdgcn_global_load_lds((const __attribute__((address_space(1))) void*)g,
                                     (__attribute__((address_space(3))) void*)l, 16, 0, 0);
}

// ---------------- prep: fp32 [R][C] -> fp16 [C][R] transpose ----------------
__global__ __launch_bounds__(256)
void prep_transpose(const float* __restrict__ w1, const float* __restrict__ w2,
                    half_t* __restrict__ ws)
{
    __shared__ half_t T[64 * 72];
    int bid = blockIdx.x;
    const float* src; half_t* dst; int R, C, r0, c0;
    if (bid < 2048) {            // W1 per e: R=512(d), C=2048(f): 8 x 32 tiles
        int e = bid >> 8, t = bid & 255;
        r0 = (t >> 5) * 64; c0 = (t & 31) * 64;
        src = w1 + (size_t)e * Dd * Ff;
        dst = ws + (size_t)e * Ff * Dd;
        R = Dd; C = Ff;
    } else {                     // W2 per e: R=2048(f), C=512(d): 32 x 8 tiles
        bid -= 2048;
        int e = bid >> 8, t = bid & 255;
        r0 = (t >> 3) * 64; c0 = (t & 7) * 64;
        src = w2 + (size_t)e * Ff * Dd;
        dst = ws + W2T_OFF + (size_t)e * Dd * Ff;
        R = Ff; C = Dd;
    }
    const int cx = threadIdx.x & 63, ry = threadIdx.x >> 6;
    #pragma unroll
    for (int j = 0; j < 16; ++j) {
        int r = ry * 16 + j;
        T[cx * 72 + r] = (half_t)src[(size_t)(r0 + r) * C + c0 + cx];
    }
    __syncthreads();
    const int rx = threadIdx.x & 7;
    #pragma unroll
    for (int it = 0; it < 2; ++it) {
        int cr = (threadIdx.x >> 3) + it * 32;
        *(half8*)&dst[(size_t)(c0 + cr) * R + r0 + rx * 8] = *(half8*)&T[cr * 72 + rx * 8];
    }
}

// ---------------- main fused MoE ----------------
// Block = (b, 64-token tile), 512 thr / 8 waves, 1 block/CU.
// launch_bounds(512,2): 256 reg/wave budget -> afrag(64 VGPR) + oacc(64 AGPR)
// + hacc + addressing fit with NO spill. (512,4) in the previous round forced
// a 128-reg cap -> 4.5 GB of scratch spill traffic, the round-2 bottleneck.
__global__ __launch_bounds__(512, 2)
void moe_main(const float* __restrict__ x, const float* __restrict__ logits,
              const int* __restrict__ masks, const half_t* __restrict__ ws,
              const float* __restrict__ b1, const float* __restrict__ b2,
              float* __restrict__ out)
{
    __shared__ half_t Wbuf[2][128 * 128];   // 2 x 32KB
    __shared__ half_t Hs[64 * 128];         // 16KB

    const int tid  = threadIdx.x;
    const int wv   = tid >> 6;
    const int lane = tid & 63;
    const int nl   = lane & 15;
    const int q    = lane >> 4;
    const int mt   = wv >> 1;     // m-tile (tokens), both phases
    const int nh   = wv & 1;      // n-split within pair

    const int bid = blockIdx.x;
    const int b   = bid & 63;     // same-b blocks land on same XCD (bid%8==b%8)
    const int l0  = (bid >> 6) * 64;

    // DMA lane decomposition
    const int rl = lane >> 4;     // row-within-4 for staging
    const int pcl = lane & 15;    // physical 16B block slot

    // ---- gates ----
    float gate[Ee];
    {
        float lg[Ee];
        float mx = -1e30f;
        #pragma unroll
        for (int e = 0; e < Ee; ++e) { lg[e] = logits[b * Ee + e]; mx = fmaxf(mx, lg[e]); }
        float s = 0.f;
        #pragma unroll
        for (int e = 0; e < Ee; ++e) { float ex = expf(lg[e] - mx); s += ex; lg[e] = ex; }
        float gs = 0.f;
        #pragma unroll
        for (int e = 0; e < Ee; ++e) {
            float r = lg[e] / s;
            r = (masks[b * Ee + e] == 1) ? r : 0.f;
            lg[e] = r; gs += r;
        }
        const float inv = 1.f / (gs + 1e-9f);
        #pragma unroll
        for (int e = 0; e < Ee; ++e) gate[e] = lg[e] * inv;
    }

    // ---- persistent X A-fragments: A[m=nl][k=q*8+j], 16 ksteps over K=512 ----
    half8 afrag[16];
    {
        const float* xrow = x + (size_t)(b * Ll + l0 + mt * 16 + nl) * Dd;
        #pragma unroll
        for (int ks = 0; ks < 16; ++ks) {
            const int c0 = ks * 32 + q * 8;
            const f32x4 u0 = *(const f32x4*)(xrow + c0);
            const f32x4 u1 = *(const f32x4*)(xrow + c0 + 4);
            half8 a;
            a[0]=(half_t)u0[0]; a[1]=(half_t)u0[1]; a[2]=(half_t)u0[2]; a[3]=(half_t)u0[3];
            a[4]=(half_t)u1[0]; a[5]=(half_t)u1[1]; a[6]=(half_t)u1[2]; a[7]=(half_t)u1[3];
            afrag[ks] = a;
        }
    }

    f32x4 oacc[16];
    #pragma unroll
    for (int i = 0; i < 16; ++i) oacc[i] = (f32x4){0.f, 0.f, 0.f, 0.f};

    #pragma unroll 1
    for (int e = 0; e < Ee; ++e) {
        const float g = gate[e];
        if (g == 0.f) continue;                       // block-uniform skip
        const half_t* W1te = ws + (size_t)e * Ff * Dd;            // [F][D]
        const half_t* W2te = ws + W2T_OFF + (size_t)e * Dd * Ff;  // [D][F]
        const float*  b1e  = b1 + (size_t)e * Ff;

        // prologue: stage A-tile (fc=0, kc=0) into buf 0
        #pragma unroll
        for (int s = 0; s < 4; ++s) {
            const int row = wv * 16 + s * 4 + rl;
            const int c = pcl ^ (row & 15);
            dma16(W1te + (size_t)row * Dd + c * 8,
                  &Wbuf[0][(wv * 16 + s * 4) * 128]);
        }

        #pragma unroll 1
        for (int fci = 0; fci < 16; ++fci) {
            const int f0 = fci * 128;
            f32x4 hacc[4];
            #pragma unroll
            for (int i = 0; i < 4; ++i) hacc[i] = (f32x4){0.f,0.f,0.f,0.f};

            // ---------- Phase A: 4 K-chunks of 128 ----------
            #pragma unroll
            for (int kc = 0; kc < 4; ++kc) {
                __syncthreads();   // buf[kc&1] DMA (issued prev step) complete
                if (kc < 3) {      // prefetch A-tile kc+1
                    #pragma unroll
                    for (int s = 0; s < 4; ++s) {
                        const int row = wv * 16 + s * 4 + rl;
                        const int c = pcl ^ (row & 15);
                        dma16(W1te + (size_t)(f0 + row) * Dd + (kc + 1) * 128 + c * 8,
                              &Wbuf[(kc & 1) ^ 1][(wv * 16 + s * 4) * 128]);
                    }
                } else {           // prefetch B-tile nc=0
                    #pragma unroll
                    for (int s = 0; s < 4; ++s) {
                        const int row = wv * 16 + s * 4 + rl;
                        const int c = pcl ^ (row & 15);
                        dma16(W2te + (size_t)row * Ff + f0 + c * 8,
                              &Wbuf[(kc & 1) ^ 1][(wv * 16 + s * 4) * 128]);
                    }
                }
                // compute from buf[kc&1]
                #pragma unroll
                for (int ks = 0; ks < 4; ++ks) {
                    const half8 a = afrag[kc * 4 + ks];
                    #pragma unroll
                    for (int nf = 0; nf < 4; ++nf) {
                        const int row = nh * 64 + nf * 16 + nl;
                        const half8 bf = *(const half8*)&Wbuf[kc & 1][row * 128 + (((ks * 4 + q) ^ nl) * 8)];
                        hacc[nf] = __builtin_amdgcn_mfma_f32_16x16x32_f16(a, bf, hacc[nf], 0, 0, 0);
                    }
                }
            }

            // ---------- epilogue A: bias + gelu + gate -> Hs (swizzled A-layout) ----------
            #pragma unroll
            for (int nf = 0; nf < 4; ++nf) {
                const int fl = nh * 64 + nf * 16 + nl;
                const float bv = b1e[f0 + fl];
                #pragma unroll
                for (int r = 0; r < 4; ++r) {
                    const int m = mt * 16 + q * 4 + r;
                    const float v  = hacc[nf][r] + bv;
                    const float gl = 0.5f * v * (1.f + erff(v * 0.70710678118654752f));
                    const int blk = (fl >> 3) ^ (m & 15);
                    Hs[m * 128 + blk * 8 + (fl & 7)] = (half_t)(g * gl);
                }
            }

            // ---------- Phase B: 4 n-chunks of 128 ----------
            half8 ha[4];
            #pragma unroll
            for (int nc = 0; nc < 4; ++nc) {
                __syncthreads();
                if (nc == 0) {     // Hs now published by all waves
                    #pragma unroll
                    for (int ks = 0; ks < 4; ++ks)
                        ha[ks] = *(const half8*)&Hs[(mt * 16 + nl) * 128 + (((ks * 4 + q) ^ nl) * 8)];
                }
                if (nc < 3) {      // prefetch B-tile nc+1
                    #pragma unroll
                    for (int s = 0; s < 4; ++s) {
                        const int row = wv * 16 + s * 4 + rl;
                        const int c = pcl ^ (row & 15);
                        dma16(W2te + (size_t)((nc + 1) * 128 + row) * Ff + f0 + c * 8,
                              &Wbuf[(nc & 1) ^ 1][(wv * 16 + s * 4) * 128]);
                    }
                } else if (fci < 15) {  // prefetch next fc A-tile kc=0
                    #pragma unroll
                    for (int s = 0; s < 4; ++s) {
                        const int row = wv * 16 + s * 4 + rl;
                        const int c = pcl ^ (row & 15);
                        dma16(W1te + (size_t)(f0 + 128 + row) * Dd + c * 8,
                              &Wbuf[(nc & 1) ^ 1][(wv * 16 + s * 4) * 128]);
                    }
                }
                // compute from buf[nc&1]
                #pragma unroll
                for (int ks = 0; ks < 4; ++ks) {
                    #pragma unroll
                    for (int t = 0; t < 4; ++t) {
                        const int lr = t * 32 + nh * 16 + nl;
                        const half8 bf = *(const half8*)&Wbuf[nc & 1][lr * 128 + (((ks * 4 + q) ^ nl) * 8)];
                        oacc[nc * 4 + t] = __builtin_amdgcn_mfma_f32_16x16x32_f16(ha[ks], bf, oacc[nc * 4 + t], 0, 0, 0);
                    }
                }
            }
        }
    }

    // ---- epilogue: add sum_e gate[e]*b2[e,:] and store fp32 ----
    #pragma unroll
    for (int nc = 0; nc < 4; ++nc) {
        #pragma unroll
        for (int t = 0; t < 4; ++t) {
            const int dcol = nc * 128 + t * 32 + nh * 16 + nl;
            float bb = 0.f;
            #pragma unroll
            for (int e = 0; e < Ee; ++e) bb += gate[e] * b2[e * Dd + dcol];
            const f32x4 v = oacc[nc * 4 + t];
            const size_t base = (size_t)(b * Ll + l0 + mt * 16 + q * 4) * Dd + dcol;
            out[base]          = v[0] + bb;
            out[base + Dd]     = v[1] + bb;
            out[base + 2 * Dd] = v[2] + bb;
            out[base + 3 * Dd] = v[3] + bb;
        }
    }
}

__global__ void moe_loss(const float* __restrict__ logits, const int* __restrict__ masks,
                         float* __restrict__ loss_out)
{
    const int b = threadIdx.x;   // 64 threads = 1 wave
    float lg[Ee];
    float mx = -1e30f;
    #pragma unroll
    for (int e = 0; e < Ee; ++e) { lg[e] = logits[b * Ee + e]; mx = fmaxf(mx, lg[e]); }
    float s = 0.f;
    #pragma unroll
    for (int e = 0; e < Ee; ++e) { float ex = expf(lg[e] - mx); s += ex; lg[e] = ex; }
    float rs = 0.f;
    #pragma unroll
    for (int e = 0; e < Ee; ++e) if (masks[b * Ee + e] == 1) rs += lg[e] / s;
    #pragma unroll
    for (int off = 32; off > 0; off >>= 1) rs += __shfl_down(rs, off);
    if (b == 0) {
        const float t = 1.f - rs / (float)Bb;
        loss_out[0] = t * t;
    }
}

extern "C" void kernel_launch(void* const* d_in, const int* in_sizes, int n_in,
                              void* d_out, int out_size, void* d_ws, size_t ws_size,
                              hipStream_t stream)
{
    const float* x      = (const float*)d_in[0];
    const float* logits = (const float*)d_in[1];
    const int*   masks  = (const int*)d_in[2];
    const float* w1     = (const float*)d_in[3];
    const float* b1     = (const float*)d_in[4];
    const float* w2     = (const float*)d_in[5];
    const float* b2     = (const float*)d_in[6];
    float* out = (float*)d_out;
    half_t* ws = (half_t*)d_ws;

    hipLaunchKernelGGL(prep_transpose, dim3(4096), dim3(256), 0, stream, w1, w2, ws);
    hipLaunchKernelGGL(moe_main, dim3(512), dim3(512), 0, stream,
                       x, logits, masks, ws, b1, b2, out);
    hipLaunchKernelGGL(moe_loss, dim3(1), dim3(64), 0, stream,
                       logits, masks, out + (size_t)Bb * Ll * Dd);
}